// Round 2
// baseline (2337.411 us; speedup 1.0000x reference)
//
#include <hip/hip_runtime.h>
#include <hip/hip_bf16.h>
#include <math.h>

#define N_USERS 100000
#define N_ITEMS 50000
#define N_EDGES 2000000
#define D 64

#define FWD_BUCKETS 782          // ceil(50000/64)
#define BWD_BUCKETS 1563         // ceil(100000/64)
#define N_BUCKETS   (FWD_BUCKETS + BWD_BUCKETS)   // 2345

// ---------------------------------------------------------------------------
// Histogram of bucket sizes (both directions) with LDS staging.
// ---------------------------------------------------------------------------
__global__ void hist_kernel(const int* __restrict__ src, const int* __restrict__ dst,
                            int* __restrict__ gh) {
    __shared__ int h[N_BUCKETS];
    for (int i = threadIdx.x; i < N_BUCKETS; i += 256) h[i] = 0;
    __syncthreads();
    int stride = gridDim.x * blockDim.x;
    for (int e = blockIdx.x * blockDim.x + threadIdx.x; e < N_EDGES; e += stride) {
        atomicAdd(&h[dst[e] >> 6], 1);
        atomicAdd(&h[FWD_BUCKETS + (src[e] >> 6)], 1);
    }
    __syncthreads();
    for (int i = threadIdx.x; i < N_BUCKETS; i += 256) {
        int v = h[i];
        if (v) atomicAdd(&gh[i], v);
    }
}

// ---------------------------------------------------------------------------
// Single-block exclusive scan; also initializes the running cursor array.
// out has n+1 entries.
// ---------------------------------------------------------------------------
__global__ void scan_excl(const int* __restrict__ in, int* __restrict__ out,
                          int* __restrict__ cur, int n) {
    const int T = 1024, E = 4;
    __shared__ int wsum[16];
    __shared__ int s_carry;
    if (threadIdx.x == 0) s_carry = 0;
    __syncthreads();

    int lane = threadIdx.x & 63;
    int wid  = threadIdx.x >> 6;

    for (int base = 0; base < n; base += T * E) {
        int idx0 = base + threadIdx.x * E;
        int v[E];
        int tot = 0;
#pragma unroll
        for (int e = 0; e < E; e++) {
            int i = idx0 + e;
            v[e] = (i < n) ? in[i] : 0;
            tot += v[e];
        }
        int incl = tot;
#pragma unroll
        for (int off = 1; off < 64; off <<= 1) {
            int t = __shfl_up(incl, off);
            if (lane >= off) incl += t;
        }
        if (lane == 63) wsum[wid] = incl;
        __syncthreads();
        if (wid == 0 && lane < 16) {
            int t = wsum[lane];
            int sc = t;
#pragma unroll
            for (int off = 1; off < 16; off <<= 1) {
                int u = __shfl_up(sc, off);
                if (lane >= off) sc += u;
            }
            wsum[lane] = sc - t;
        }
        __syncthreads();
        int wave_off = wsum[wid];
        int excl = s_carry + wave_off + incl - tot;
#pragma unroll
        for (int e = 0; e < E; e++) {
            int i = idx0 + e;
            if (i < n) { out[i] = excl; cur[i] = excl; }
            excl += v[e];
        }
        __syncthreads();
        if (threadIdx.x == T - 1) s_carry += wave_off + incl;
        __syncthreads();
    }
    if (threadIdx.x == 0) out[n] = s_carry;
}

// ---------------------------------------------------------------------------
// Fill packed bucket entries: fwd = s | d_local<<17, bwd = d | s_local<<16.
// ---------------------------------------------------------------------------
__global__ void fill_kernel(const int* __restrict__ src, const int* __restrict__ dst,
                            int* __restrict__ cur, unsigned* __restrict__ buf) {
    int stride = gridDim.x * blockDim.x;
    for (int e = blockIdx.x * blockDim.x + threadIdx.x; e < N_EDGES; e += stride) {
        int s = src[e], d = dst[e];
        int p = atomicAdd(&cur[d >> 6], 1);
        buf[p] = (unsigned)s | ((unsigned)(d & 63) << 17);
        int q = atomicAdd(&cur[FWD_BUCKETS + (s >> 6)], 1);
        buf[q] = (unsigned)d | ((unsigned)(s & 63) << 16);
    }
}

// ---------------------------------------------------------------------------
// Global softmax stats over edge_w[N_ITEMS]: stats[0]=max, stats[1]=sum(exp(x-max))
// ---------------------------------------------------------------------------
__global__ void softmax_stats_kernel(const float* __restrict__ w, float* __restrict__ stats) {
    __shared__ float red[16];
    int tid = threadIdx.x, lane = tid & 63, wid = tid >> 6;

    float m = -INFINITY;
    for (int i = tid; i < N_ITEMS; i += 1024) m = fmaxf(m, w[i]);
#pragma unroll
    for (int off = 32; off; off >>= 1) m = fmaxf(m, __shfl_xor(m, off));
    if (lane == 0) red[wid] = m;
    __syncthreads();
    if (tid == 0) {
        float t = red[0];
        for (int k = 1; k < 16; k++) t = fmaxf(t, red[k]);
        red[0] = t;
    }
    __syncthreads();
    m = red[0];
    __syncthreads();

    float s = 0.f;
    for (int i = tid; i < N_ITEMS; i += 1024) s += expf(w[i] - m);
#pragma unroll
    for (int off = 32; off; off >>= 1) s += __shfl_xor(s, off);
    if (lane == 0) red[wid] = s;
    __syncthreads();
    if (tid == 0) {
        float t = 0.f;
        for (int k = 0; k < 16; k++) t += red[k];
        stats[0] = m;
        stats[1] = t;
    }
}

// ---------------------------------------------------------------------------
// Forward: one WG per 64-item bucket. LDS 64x64 accumulator, wave-per-edge
// row gather (lane = feature), fused epilogue.
// ---------------------------------------------------------------------------
__global__ __launch_bounds__(256) void fwd_bucket_kernel(
    const float* __restrict__ h_user, const float* __restrict__ pf,
    const float* __restrict__ edge_w, const unsigned* __restrict__ buf,
    const int* __restrict__ off, const float* __restrict__ stats,
    float* __restrict__ rst) {
    __shared__ float acc[64 * 64];   // 16 KB
    __shared__ int degs[64];
    int b = blockIdx.x;
    int tid = threadIdx.x, lane = tid & 63, wv = tid >> 6;

    for (int i = tid; i < 64 * 64; i += 256) acc[i] = 0.f;
    if (tid < 64) degs[tid] = 0;
    __syncthreads();

    int beg = off[b], end = off[b + 1];
    for (int t = beg + wv * 64; t < end; t += 256) {
        int navail = end - t; if (navail > 64) navail = 64;
        unsigned ent = 0;
        if (lane < navail) ent = buf[t + lane];
#pragma unroll 4
        for (int j = 0; j < navail; j++) {
            unsigned e = __shfl(ent, j);
            int s  = (int)(e & 0x1FFFFu);
            int dl = (int)(e >> 17);
            float v = h_user[(size_t)s * D + lane];
            atomicAdd(&acc[dl * 64 + lane], v);
            if (lane == 0) atomicAdd(&degs[dl], 1);
        }
    }
    __syncthreads();

    float m = stats[0], ssum = stats[1];
    for (int il = wv; il < 64; il += 4) {
        int i = b * 64 + il;
        if (i >= N_ITEMS) break;
        float deg = (float)degs[il];
        if (deg < 1.f) deg = 1.f;
        float sc = expf(edge_w[i] - m) / (ssum * deg);
        float val = (acc[il * 64 + lane] + 0.5f * tanhf(pf[(size_t)i * D + lane])) * sc;
        rst[(size_t)i * D + lane] = val;
    }
}

// ---------------------------------------------------------------------------
// Backward: one WG per 64-user bucket; out[u] = sum rst[d] / deg_src[u].
// ---------------------------------------------------------------------------
__global__ __launch_bounds__(256) void bwd_bucket_kernel(
    const float* __restrict__ rst, const unsigned* __restrict__ buf,
    const int* __restrict__ off, float* __restrict__ out) {
    __shared__ float acc[64 * 64];
    __shared__ int degs[64];
    int b = blockIdx.x;
    int tid = threadIdx.x, lane = tid & 63, wv = tid >> 6;

    for (int i = tid; i < 64 * 64; i += 256) acc[i] = 0.f;
    if (tid < 64) degs[tid] = 0;
    __syncthreads();

    int beg = off[FWD_BUCKETS + b], end = off[FWD_BUCKETS + b + 1];
    for (int t = beg + wv * 64; t < end; t += 256) {
        int navail = end - t; if (navail > 64) navail = 64;
        unsigned ent = 0;
        if (lane < navail) ent = buf[t + lane];
#pragma unroll 4
        for (int j = 0; j < navail; j++) {
            unsigned e = __shfl(ent, j);
            int d  = (int)(e & 0xFFFFu);
            int sl = (int)(e >> 16);
            float v = rst[(size_t)d * D + lane];
            atomicAdd(&acc[sl * 64 + lane], v);
            if (lane == 0) atomicAdd(&degs[sl], 1);
        }
    }
    __syncthreads();

    for (int il = wv; il < 64; il += 4) {
        int u = b * 64 + il;
        if (u >= N_USERS) break;
        float deg = (float)degs[il];
        if (deg < 1.f) deg = 1.f;
        out[(size_t)u * D + lane] = acc[il * 64 + lane] / deg;
    }
}

// ---------------------------------------------------------------------------
extern "C" void kernel_launch(void* const* d_in, const int* in_sizes, int n_in,
                              void* d_out, int out_size, void* d_ws, size_t ws_size,
                              hipStream_t stream) {
    const float* h_user = (const float*)d_in[0];   // [N_USERS, D]
    const float* pf     = (const float*)d_in[1];   // [N_ITEMS, D]
    const float* edge_w = (const float*)d_in[2];   // [N_ITEMS]
    const int*   src    = (const int*)d_in[3];     // [N_EDGES]
    const int*   dst    = (const int*)d_in[4];     // [N_EDGES]
    float* out = (float*)d_out;                    // [N_USERS, D]

    // workspace carve-up (~29 MB)
    char* p = (char*)d_ws;
    int* gh   = (int*)p;      p += sizeof(int) * N_BUCKETS;
    int* off  = (int*)p;      p += sizeof(int) * (N_BUCKETS + 1);
    int* cur  = (int*)p;      p += sizeof(int) * N_BUCKETS;
    unsigned* buf = (unsigned*)p; p += sizeof(unsigned) * (size_t)2 * N_EDGES;
    float* rst   = (float*)p; p += sizeof(float) * (size_t)N_ITEMS * D;
    float* stats = (float*)p; p += 2 * sizeof(float);

    hipMemsetAsync(gh, 0, sizeof(int) * N_BUCKETS, stream);

    hist_kernel<<<256, 256, 0, stream>>>(src, dst, gh);
    scan_excl<<<1, 1024, 0, stream>>>(gh, off, cur, N_BUCKETS);
    fill_kernel<<<2048, 256, 0, stream>>>(src, dst, cur, buf);
    softmax_stats_kernel<<<1, 1024, 0, stream>>>(edge_w, stats);
    fwd_bucket_kernel<<<FWD_BUCKETS, 256, 0, stream>>>(h_user, pf, edge_w, buf, off, stats, rst);
    bwd_bucket_kernel<<<BWD_BUCKETS, 256, 0, stream>>>(rst, buf, off, out);
}

// Round 3
// 2208.321 us; speedup vs baseline: 1.0585x; 1.0585x over previous
//
#include <hip/hip_runtime.h>
#include <hip/hip_bf16.h>
#include <math.h>

#define N_USERS 100000
#define N_ITEMS 50000
#define N_EDGES 2000000
#define D 64

#define FWD_BUCKETS 782          // ceil(50000/64)
#define BWD_BUCKETS 1563         // ceil(100000/64)
#define N_BUCKETS   (FWD_BUCKETS + BWD_BUCKETS)   // 2345

// ---------------------------------------------------------------------------
// Histogram of bucket sizes (both directions) with LDS staging.
// ---------------------------------------------------------------------------
__global__ void hist_kernel(const int* __restrict__ src, const int* __restrict__ dst,
                            int* __restrict__ gh) {
    __shared__ int h[N_BUCKETS];
    for (int i = threadIdx.x; i < N_BUCKETS; i += 256) h[i] = 0;
    __syncthreads();
    int stride = gridDim.x * blockDim.x;
    for (int e = blockIdx.x * blockDim.x + threadIdx.x; e < N_EDGES; e += stride) {
        atomicAdd(&h[dst[e] >> 6], 1);
        atomicAdd(&h[FWD_BUCKETS + (src[e] >> 6)], 1);
    }
    __syncthreads();
    for (int i = threadIdx.x; i < N_BUCKETS; i += 256) {
        int v = h[i];
        if (v) atomicAdd(&gh[i], v);
    }
}

// ---------------------------------------------------------------------------
// Single-block exclusive scan; also initializes the running cursor array.
// out has n+1 entries.
// ---------------------------------------------------------------------------
__global__ void scan_excl(const int* __restrict__ in, int* __restrict__ out,
                          int* __restrict__ cur, int n) {
    const int T = 1024, E = 4;
    __shared__ int wsum[16];
    __shared__ int s_carry;
    if (threadIdx.x == 0) s_carry = 0;
    __syncthreads();

    int lane = threadIdx.x & 63;
    int wid  = threadIdx.x >> 6;

    for (int base = 0; base < n; base += T * E) {
        int idx0 = base + threadIdx.x * E;
        int v[E];
        int tot = 0;
#pragma unroll
        for (int e = 0; e < E; e++) {
            int i = idx0 + e;
            v[e] = (i < n) ? in[i] : 0;
            tot += v[e];
        }
        int incl = tot;
#pragma unroll
        for (int off = 1; off < 64; off <<= 1) {
            int t = __shfl_up(incl, off);
            if (lane >= off) incl += t;
        }
        if (lane == 63) wsum[wid] = incl;
        __syncthreads();
        if (wid == 0 && lane < 16) {
            int t = wsum[lane];
            int sc = t;
#pragma unroll
            for (int off = 1; off < 16; off <<= 1) {
                int u = __shfl_up(sc, off);
                if (lane >= off) sc += u;
            }
            wsum[lane] = sc - t;
        }
        __syncthreads();
        int wave_off = wsum[wid];
        int excl = s_carry + wave_off + incl - tot;
#pragma unroll
        for (int e = 0; e < E; e++) {
            int i = idx0 + e;
            if (i < n) { out[i] = excl; cur[i] = excl; }
            excl += v[e];
        }
        __syncthreads();
        if (threadIdx.x == T - 1) s_carry += wave_off + incl;
        __syncthreads();
    }
    if (threadIdx.x == 0) out[n] = s_carry;
}

// ---------------------------------------------------------------------------
// Fill packed bucket entries: fwd = s | d_local<<17, bwd = d | s_local<<16.
// ---------------------------------------------------------------------------
__global__ void fill_kernel(const int* __restrict__ src, const int* __restrict__ dst,
                            int* __restrict__ cur, unsigned* __restrict__ buf) {
    int stride = gridDim.x * blockDim.x;
    for (int e = blockIdx.x * blockDim.x + threadIdx.x; e < N_EDGES; e += stride) {
        int s = src[e], d = dst[e];
        int p = atomicAdd(&cur[d >> 6], 1);
        buf[p] = (unsigned)s | ((unsigned)(d & 63) << 17);
        int q = atomicAdd(&cur[FWD_BUCKETS + (s >> 6)], 1);
        buf[q] = (unsigned)d | ((unsigned)(s & 63) << 16);
    }
}

// ---------------------------------------------------------------------------
// Global softmax stats over edge_w[N_ITEMS]: stats[0]=max, stats[1]=sum(exp(x-max))
// ---------------------------------------------------------------------------
__global__ void softmax_stats_kernel(const float* __restrict__ w, float* __restrict__ stats) {
    __shared__ float red[16];
    int tid = threadIdx.x, lane = tid & 63, wid = tid >> 6;

    float m = -INFINITY;
    for (int i = tid; i < N_ITEMS; i += 1024) m = fmaxf(m, w[i]);
#pragma unroll
    for (int off = 32; off; off >>= 1) m = fmaxf(m, __shfl_xor(m, off));
    if (lane == 0) red[wid] = m;
    __syncthreads();
    if (tid == 0) {
        float t = red[0];
        for (int k = 1; k < 16; k++) t = fmaxf(t, red[k]);
        red[0] = t;
    }
    __syncthreads();
    m = red[0];
    __syncthreads();

    float s = 0.f;
    for (int i = tid; i < N_ITEMS; i += 1024) s += expf(w[i] - m);
#pragma unroll
    for (int off = 32; off; off >>= 1) s += __shfl_xor(s, off);
    if (lane == 0) red[wid] = s;
    __syncthreads();
    if (tid == 0) {
        float t = 0.f;
        for (int k = 0; k < 16; k++) t += red[k];
        stats[0] = m;
        stats[1] = t;
    }
}

// ---------------------------------------------------------------------------
// Forward: one WG (512 threads) per 64-item bucket. Edge-parallel: 32 threads
// per edge, thread handles features q and q+32. LDS 64x64 accumulator
// (ds_add banks = q mod 32 -> 2 lanes/bank, conflict-free). Fused epilogue.
// ---------------------------------------------------------------------------
__global__ __launch_bounds__(512) void fwd_bucket_kernel(
    const float* __restrict__ h_user, const float* __restrict__ pf,
    const float* __restrict__ edge_w, const unsigned* __restrict__ buf,
    const int* __restrict__ off, const float* __restrict__ stats,
    float* __restrict__ rst) {
    __shared__ float acc[64 * 64];   // 16 KB
    __shared__ int degs[64];
    int b = blockIdx.x;
    int tid = threadIdx.x;
    int q = tid & 31;        // feature lane (0..31)
    int el = tid >> 5;       // edge slot within pass (0..15)

    for (int i = tid; i < 64 * 64; i += 512) acc[i] = 0.f;
    if (tid < 64) degs[tid] = 0;
    __syncthreads();

    int beg = off[b], end = off[b + 1];
    int n = end - beg;
    int n_full = n >> 4;     // full passes of 16 edges
    for (int p = 0; p < n_full; p++) {
        int e = beg + p * 16 + el;
        unsigned ent = buf[e];
        int s  = (int)(ent & 0x1FFFFu);
        int dl = (int)(ent >> 17);
        float v0 = h_user[(size_t)s * D + q];
        float v1 = h_user[(size_t)s * D + q + 32];
        atomicAdd(&acc[dl * 64 + q], v0);
        atomicAdd(&acc[dl * 64 + q + 32], v1);
        if (q == 0) atomicAdd(&degs[dl], 1);
    }
    // tail
    {
        int e = beg + n_full * 16 + el;
        if (e < end) {
            unsigned ent = buf[e];
            int s  = (int)(ent & 0x1FFFFu);
            int dl = (int)(ent >> 17);
            float v0 = h_user[(size_t)s * D + q];
            float v1 = h_user[(size_t)s * D + q + 32];
            atomicAdd(&acc[dl * 64 + q], v0);
            atomicAdd(&acc[dl * 64 + q + 32], v1);
            if (q == 0) atomicAdd(&degs[dl], 1);
        }
    }
    __syncthreads();

    int lane = tid & 63, wv = tid >> 6;   // 8 waves
    float m = stats[0], ssum = stats[1];
    for (int il = wv; il < 64; il += 8) {
        int i = b * 64 + il;
        if (i >= N_ITEMS) break;
        float deg = (float)degs[il];
        if (deg < 1.f) deg = 1.f;
        float sc = expf(edge_w[i] - m) / (ssum * deg);
        float val = (acc[il * 64 + lane] + 0.5f * tanhf(pf[(size_t)i * D + lane])) * sc;
        rst[(size_t)i * D + lane] = val;
    }
}

// ---------------------------------------------------------------------------
// Backward: one WG (512 threads) per 64-user bucket; same edge-parallel plan.
// ---------------------------------------------------------------------------
__global__ __launch_bounds__(512) void bwd_bucket_kernel(
    const float* __restrict__ rst, const unsigned* __restrict__ buf,
    const int* __restrict__ off, float* __restrict__ out) {
    __shared__ float acc[64 * 64];
    __shared__ int degs[64];
    int b = blockIdx.x;
    int tid = threadIdx.x;
    int q = tid & 31;
    int el = tid >> 5;

    for (int i = tid; i < 64 * 64; i += 512) acc[i] = 0.f;
    if (tid < 64) degs[tid] = 0;
    __syncthreads();

    int beg = off[FWD_BUCKETS + b], end = off[FWD_BUCKETS + b + 1];
    int n = end - beg;
    int n_full = n >> 4;
    for (int p = 0; p < n_full; p++) {
        int e = beg + p * 16 + el;
        unsigned ent = buf[e];
        int d  = (int)(ent & 0xFFFFu);
        int sl = (int)(ent >> 16);
        float v0 = rst[(size_t)d * D + q];
        float v1 = rst[(size_t)d * D + q + 32];
        atomicAdd(&acc[sl * 64 + q], v0);
        atomicAdd(&acc[sl * 64 + q + 32], v1);
        if (q == 0) atomicAdd(&degs[sl], 1);
    }
    {
        int e = beg + n_full * 16 + el;
        if (e < end) {
            unsigned ent = buf[e];
            int d  = (int)(ent & 0xFFFFu);
            int sl = (int)(ent >> 16);
            float v0 = rst[(size_t)d * D + q];
            float v1 = rst[(size_t)d * D + q + 32];
            atomicAdd(&acc[sl * 64 + q], v0);
            atomicAdd(&acc[sl * 64 + q + 32], v1);
            if (q == 0) atomicAdd(&degs[sl], 1);
        }
    }
    __syncthreads();

    int lane = tid & 63, wv = tid >> 6;
    for (int il = wv; il < 64; il += 8) {
        int u = b * 64 + il;
        if (u >= N_USERS) break;
        float deg = (float)degs[il];
        if (deg < 1.f) deg = 1.f;
        out[(size_t)u * D + lane] = acc[il * 64 + lane] / deg;
    }
}

// ---------------------------------------------------------------------------
extern "C" void kernel_launch(void* const* d_in, const int* in_sizes, int n_in,
                              void* d_out, int out_size, void* d_ws, size_t ws_size,
                              hipStream_t stream) {
    const float* h_user = (const float*)d_in[0];   // [N_USERS, D]
    const float* pf     = (const float*)d_in[1];   // [N_ITEMS, D]
    const float* edge_w = (const float*)d_in[2];   // [N_ITEMS]
    const int*   src    = (const int*)d_in[3];     // [N_EDGES]
    const int*   dst    = (const int*)d_in[4];     // [N_EDGES]
    float* out = (float*)d_out;                    // [N_USERS, D]

    // workspace carve-up (~29 MB)
    char* p = (char*)d_ws;
    int* gh   = (int*)p;      p += sizeof(int) * N_BUCKETS;
    int* off  = (int*)p;      p += sizeof(int) * (N_BUCKETS + 1);
    int* cur  = (int*)p;      p += sizeof(int) * N_BUCKETS;
    unsigned* buf = (unsigned*)p; p += sizeof(unsigned) * (size_t)2 * N_EDGES;
    float* rst   = (float*)p; p += sizeof(float) * (size_t)N_ITEMS * D;
    float* stats = (float*)p; p += 2 * sizeof(float);

    hipMemsetAsync(gh, 0, sizeof(int) * N_BUCKETS, stream);

    hist_kernel<<<256, 256, 0, stream>>>(src, dst, gh);
    scan_excl<<<1, 1024, 0, stream>>>(gh, off, cur, N_BUCKETS);
    fill_kernel<<<2048, 256, 0, stream>>>(src, dst, cur, buf);
    softmax_stats_kernel<<<1, 1024, 0, stream>>>(edge_w, stats);
    fwd_bucket_kernel<<<FWD_BUCKETS, 512, 0, stream>>>(h_user, pf, edge_w, buf, off, stats, rst);
    bwd_bucket_kernel<<<BWD_BUCKETS, 512, 0, stream>>>(rst, buf, off, out);
}

// Round 4
// 1977.795 us; speedup vs baseline: 1.1818x; 1.1166x over previous
//
#include <hip/hip_runtime.h>
#include <hip/hip_bf16.h>
#include <math.h>

#define N_USERS 100000
#define N_ITEMS 50000
#define N_EDGES 2000000
#define D 64

#define FWD_BUCKETS 782            // ceil(50000/64)  (items)
#define BWD_BUCKETS 1563           // ceil(100000/64) (users)
// fwd cell key = (dst>>6)<<4 | (src>>13)   : 16 src segments (0..12 used)
// bwd cell key = (src>>6)<<3 | (dst>>13)   :  8 dst segments (0..6 used)
#define NF_CELLS (FWD_BUCKETS * 16)          // 12512
#define NB_CELLS (BWD_BUCKETS * 8)           // 12504
#define N_CELLS  (NF_CELLS + NB_CELLS)       // 25016

__device__ __forceinline__ int fwd_key(int s, int d) { return ((d >> 6) << 4) | (s >> 13); }
__device__ __forceinline__ int bwd_key(int s, int d) { return NF_CELLS + (((s >> 6) << 3) | (d >> 13)); }

// ---------------------------------------------------------------------------
// Histograms of cell sizes (separate kernels keep static LDS <= 50 KB each).
// ---------------------------------------------------------------------------
__global__ void hist_fwd_kernel(const int* __restrict__ src, const int* __restrict__ dst,
                                int* __restrict__ gh) {
    __shared__ int h[NF_CELLS];
    for (int i = threadIdx.x; i < NF_CELLS; i += 256) h[i] = 0;
    __syncthreads();
    int stride = gridDim.x * blockDim.x;
    for (int e = blockIdx.x * blockDim.x + threadIdx.x; e < N_EDGES; e += stride)
        atomicAdd(&h[fwd_key(src[e], dst[e])], 1);
    __syncthreads();
    for (int i = threadIdx.x; i < NF_CELLS; i += 256) {
        int v = h[i];
        if (v) atomicAdd(&gh[i], v);
    }
}

__global__ void hist_bwd_kernel(const int* __restrict__ src, const int* __restrict__ dst,
                                int* __restrict__ gh) {
    __shared__ int h[NB_CELLS];
    for (int i = threadIdx.x; i < NB_CELLS; i += 256) h[i] = 0;
    __syncthreads();
    int stride = gridDim.x * blockDim.x;
    for (int e = blockIdx.x * blockDim.x + threadIdx.x; e < N_EDGES; e += stride)
        atomicAdd(&h[bwd_key(src[e], dst[e]) - NF_CELLS], 1);
    __syncthreads();
    for (int i = threadIdx.x; i < NB_CELLS; i += 256) {
        int v = h[i];
        if (v) atomicAdd(&gh[NF_CELLS + i], v);
    }
}

// ---------------------------------------------------------------------------
// Single-block exclusive scan; also initializes the running cursor array.
// ---------------------------------------------------------------------------
__global__ void scan_excl(const int* __restrict__ in, int* __restrict__ out,
                          int* __restrict__ cur, int n) {
    const int T = 1024, E = 4;
    __shared__ int wsum[16];
    __shared__ int s_carry;
    if (threadIdx.x == 0) s_carry = 0;
    __syncthreads();

    int lane = threadIdx.x & 63;
    int wid  = threadIdx.x >> 6;

    for (int base = 0; base < n; base += T * E) {
        int idx0 = base + threadIdx.x * E;
        int v[E];
        int tot = 0;
#pragma unroll
        for (int e = 0; e < E; e++) {
            int i = idx0 + e;
            v[e] = (i < n) ? in[i] : 0;
            tot += v[e];
        }
        int incl = tot;
#pragma unroll
        for (int off = 1; off < 64; off <<= 1) {
            int t = __shfl_up(incl, off);
            if (lane >= off) incl += t;
        }
        if (lane == 63) wsum[wid] = incl;
        __syncthreads();
        if (wid == 0 && lane < 16) {
            int t = wsum[lane];
            int sc = t;
#pragma unroll
            for (int off = 1; off < 16; off <<= 1) {
                int u = __shfl_up(sc, off);
                if (lane >= off) sc += u;
            }
            wsum[lane] = sc - t;
        }
        __syncthreads();
        int wave_off = wsum[wid];
        int excl = s_carry + wave_off + incl - tot;
#pragma unroll
        for (int e = 0; e < E; e++) {
            int i = idx0 + e;
            if (i < n) { out[i] = excl; cur[i] = excl; }
            excl += v[e];
        }
        __syncthreads();
        if (threadIdx.x == T - 1) s_carry += wave_off + incl;
        __syncthreads();
    }
    if (threadIdx.x == 0) out[n] = s_carry;
}

// ---------------------------------------------------------------------------
// Fill, XCD-class partitioned: blockIdx%8 = class; WG only emits entries whose
// cell % 8 == class, so each cell's output stream is written from one XCD's L2
// (kills cross-XCD partial-line writeback amplification). Edge data read 8x
// (128 MB streaming, cheap). NF_CELLS % 8 == 0 so bwd keys keep class = key%8.
// ---------------------------------------------------------------------------
__global__ void fill_kernel(const int* __restrict__ src, const int* __restrict__ dst,
                            int* __restrict__ cur, unsigned* __restrict__ buf) {
    int cls   = blockIdx.x & 7;
    int slice = blockIdx.x >> 3;               // 0..255
    const int per = (N_EDGES + 255) / 256;     // 7813
    int lo = slice * per;
    int hi = lo + per; if (hi > N_EDGES) hi = N_EDGES;
    for (int e = lo + threadIdx.x; e < hi; e += 256) {
        int s = src[e], d = dst[e];
        int kf = fwd_key(s, d);
        if ((kf & 7) == cls) {
            int p = atomicAdd(&cur[kf], 1);
            buf[p] = (unsigned)s | ((unsigned)(d & 63) << 17);
        }
        int kb = bwd_key(s, d);
        if ((kb & 7) == cls) {
            int p = atomicAdd(&cur[kb], 1);
            buf[p] = (unsigned)d | ((unsigned)(s & 63) << 16);
        }
    }
}

// ---------------------------------------------------------------------------
// Global softmax stats over edge_w[N_ITEMS]: stats[0]=max, stats[1]=sum(exp(x-max))
// ---------------------------------------------------------------------------
__global__ void softmax_stats_kernel(const float* __restrict__ w, float* __restrict__ stats) {
    __shared__ float red[16];
    int tid = threadIdx.x, lane = tid & 63, wid = tid >> 6;

    float m = -INFINITY;
    for (int i = tid; i < N_ITEMS; i += 1024) m = fmaxf(m, w[i]);
#pragma unroll
    for (int off = 32; off; off >>= 1) m = fmaxf(m, __shfl_xor(m, off));
    if (lane == 0) red[wid] = m;
    __syncthreads();
    if (tid == 0) {
        float t = red[0];
        for (int k = 1; k < 16; k++) t = fmaxf(t, red[k]);
        red[0] = t;
    }
    __syncthreads();
    m = red[0];
    __syncthreads();

    float s = 0.f;
    for (int i = tid; i < N_ITEMS; i += 1024) s += expf(w[i] - m);
#pragma unroll
    for (int off = 32; off; off >>= 1) s += __shfl_xor(s, off);
    if (lane == 0) red[wid] = s;
    __syncthreads();
    if (tid == 0) {
        float t = 0.f;
        for (int k = 0; k < 16; k++) t += red[k];
        stats[0] = m;
        stats[1] = t;
    }
}

// ---------------------------------------------------------------------------
// Forward: one WG (512 threads) per 64-item bucket. Edges arrive src-coarse-
// sorted (2 MB windows, L2-resident). 32 threads/edge, float2 per thread,
// 4 edges in flight per wave. LDS 64x64 accumulator + fused epilogue.
// ---------------------------------------------------------------------------
__global__ __launch_bounds__(512) void fwd_bucket_kernel(
    const float* __restrict__ h_user, const float* __restrict__ pf,
    const float* __restrict__ edge_w, const unsigned* __restrict__ buf,
    const int* __restrict__ off, const float* __restrict__ stats,
    float* __restrict__ rst) {
    __shared__ float acc[64 * 64];   // 16 KB
    __shared__ int degs[64];
    int b = blockIdx.x;
    int tid = threadIdx.x;
    int q  = tid & 31;        // feature-pair index (covers 2q, 2q+1)
    int el = tid >> 5;        // edge slot (0..15)

    for (int i = tid; i < 64 * 64; i += 512) acc[i] = 0.f;
    if (tid < 64) degs[tid] = 0;
    __syncthreads();

    const float2* H = (const float2*)h_user;
    int beg = off[b << 4], end = off[(b + 1) << 4];
    int n = end - beg;
    int nsup = n >> 6;        // 64-edge superpasses
    for (int p = 0; p < nsup; p++) {
        int base = beg + (p << 6);
        unsigned e0 = buf[base + el];
        unsigned e1 = buf[base + 16 + el];
        unsigned e2 = buf[base + 32 + el];
        unsigned e3 = buf[base + 48 + el];
        float2 v0 = H[((e0 & 0x1FFFFu) << 5) + q];
        float2 v1 = H[((e1 & 0x1FFFFu) << 5) + q];
        float2 v2 = H[((e2 & 0x1FFFFu) << 5) + q];
        float2 v3 = H[((e3 & 0x1FFFFu) << 5) + q];
        int d0 = e0 >> 17, d1 = e1 >> 17, d2 = e2 >> 17, d3 = e3 >> 17;
        atomicAdd(&acc[(d0 << 6) + (q << 1)],     v0.x);
        atomicAdd(&acc[(d0 << 6) + (q << 1) + 1], v0.y);
        atomicAdd(&acc[(d1 << 6) + (q << 1)],     v1.x);
        atomicAdd(&acc[(d1 << 6) + (q << 1) + 1], v1.y);
        atomicAdd(&acc[(d2 << 6) + (q << 1)],     v2.x);
        atomicAdd(&acc[(d2 << 6) + (q << 1) + 1], v2.y);
        atomicAdd(&acc[(d3 << 6) + (q << 1)],     v3.x);
        atomicAdd(&acc[(d3 << 6) + (q << 1) + 1], v3.y);
        if (q == 0) {
            atomicAdd(&degs[d0], 1); atomicAdd(&degs[d1], 1);
            atomicAdd(&degs[d2], 1); atomicAdd(&degs[d3], 1);
        }
    }
    for (int e = beg + (nsup << 6) + el; e < end; e += 16) {
        unsigned ent = buf[e];
        float2 v = H[((ent & 0x1FFFFu) << 5) + q];
        int dl = ent >> 17;
        atomicAdd(&acc[(dl << 6) + (q << 1)],     v.x);
        atomicAdd(&acc[(dl << 6) + (q << 1) + 1], v.y);
        if (q == 0) atomicAdd(&degs[dl], 1);
    }
    __syncthreads();

    int lane = tid & 63, wv = tid >> 6;   // 8 waves
    float m = stats[0], ssum = stats[1];
    for (int il = wv; il < 64; il += 8) {
        int i = b * 64 + il;
        if (i >= N_ITEMS) break;
        float deg = (float)degs[il];
        if (deg < 1.f) deg = 1.f;
        float sc = expf(edge_w[i] - m) / (ssum * deg);
        float val = (acc[il * 64 + lane] + 0.5f * tanhf(pf[(size_t)i * D + lane])) * sc;
        rst[(size_t)i * D + lane] = val;
    }
}

// ---------------------------------------------------------------------------
// Backward: one WG (512 threads) per 64-user bucket; same plan over rst.
// ---------------------------------------------------------------------------
__global__ __launch_bounds__(512) void bwd_bucket_kernel(
    const float* __restrict__ rst, const unsigned* __restrict__ buf,
    const int* __restrict__ off, float* __restrict__ out) {
    __shared__ float acc[64 * 64];
    __shared__ int degs[64];
    int b = blockIdx.x;
    int tid = threadIdx.x;
    int q  = tid & 31;
    int el = tid >> 5;

    for (int i = tid; i < 64 * 64; i += 512) acc[i] = 0.f;
    if (tid < 64) degs[tid] = 0;
    __syncthreads();

    const float2* R = (const float2*)rst;
    int beg = off[NF_CELLS + (b << 3)], end = off[NF_CELLS + ((b + 1) << 3)];
    int n = end - beg;
    int nsup = n >> 6;
    for (int p = 0; p < nsup; p++) {
        int base = beg + (p << 6);
        unsigned e0 = buf[base + el];
        unsigned e1 = buf[base + 16 + el];
        unsigned e2 = buf[base + 32 + el];
        unsigned e3 = buf[base + 48 + el];
        float2 v0 = R[((e0 & 0xFFFFu) << 5) + q];
        float2 v1 = R[((e1 & 0xFFFFu) << 5) + q];
        float2 v2 = R[((e2 & 0xFFFFu) << 5) + q];
        float2 v3 = R[((e3 & 0xFFFFu) << 5) + q];
        int s0 = e0 >> 16, s1 = e1 >> 16, s2 = e2 >> 16, s3 = e3 >> 16;
        atomicAdd(&acc[(s0 << 6) + (q << 1)],     v0.x);
        atomicAdd(&acc[(s0 << 6) + (q << 1) + 1], v0.y);
        atomicAdd(&acc[(s1 << 6) + (q << 1)],     v1.x);
        atomicAdd(&acc[(s1 << 6) + (q << 1) + 1], v1.y);
        atomicAdd(&acc[(s2 << 6) + (q << 1)],     v2.x);
        atomicAdd(&acc[(s2 << 6) + (q << 1) + 1], v2.y);
        atomicAdd(&acc[(s3 << 6) + (q << 1)],     v3.x);
        atomicAdd(&acc[(s3 << 6) + (q << 1) + 1], v3.y);
        if (q == 0) {
            atomicAdd(&degs[s0], 1); atomicAdd(&degs[s1], 1);
            atomicAdd(&degs[s2], 1); atomicAdd(&degs[s3], 1);
        }
    }
    for (int e = beg + (nsup << 6) + el; e < end; e += 16) {
        unsigned ent = buf[e];
        float2 v = R[((ent & 0xFFFFu) << 5) + q];
        int sl = ent >> 16;
        atomicAdd(&acc[(sl << 6) + (q << 1)],     v.x);
        atomicAdd(&acc[(sl << 6) + (q << 1) + 1], v.y);
        if (q == 0) atomicAdd(&degs[sl], 1);
    }
    __syncthreads();

    int lane = tid & 63, wv = tid >> 6;
    for (int il = wv; il < 64; il += 8) {
        int u = b * 64 + il;
        if (u >= N_USERS) break;
        float deg = (float)degs[il];
        if (deg < 1.f) deg = 1.f;
        out[(size_t)u * D + lane] = acc[il * 64 + lane] / deg;
    }
}

// ---------------------------------------------------------------------------
extern "C" void kernel_launch(void* const* d_in, const int* in_sizes, int n_in,
                              void* d_out, int out_size, void* d_ws, size_t ws_size,
                              hipStream_t stream) {
    const float* h_user = (const float*)d_in[0];   // [N_USERS, D]
    const float* pf     = (const float*)d_in[1];   // [N_ITEMS, D]
    const float* edge_w = (const float*)d_in[2];   // [N_ITEMS]
    const int*   src    = (const int*)d_in[3];     // [N_EDGES]
    const int*   dst    = (const int*)d_in[4];     // [N_EDGES]
    float* out = (float*)d_out;                    // [N_USERS, D]

    // workspace carve-up (~29.3 MB)
    char* p = (char*)d_ws;
    int* gh   = (int*)p;      p += sizeof(int) * N_CELLS;
    int* off  = (int*)p;      p += sizeof(int) * (N_CELLS + 1);
    int* cur  = (int*)p;      p += sizeof(int) * N_CELLS;
    unsigned* buf = (unsigned*)p; p += sizeof(unsigned) * (size_t)2 * N_EDGES;
    float* rst   = (float*)p; p += sizeof(float) * (size_t)N_ITEMS * D;
    float* stats = (float*)p; p += 2 * sizeof(float);

    hipMemsetAsync(gh, 0, sizeof(int) * N_CELLS, stream);

    hist_fwd_kernel<<<64, 256, 0, stream>>>(src, dst, gh);
    hist_bwd_kernel<<<64, 256, 0, stream>>>(src, dst, gh);
    scan_excl<<<1, 1024, 0, stream>>>(gh, off, cur, N_CELLS);
    fill_kernel<<<2048, 256, 0, stream>>>(src, dst, cur, buf);
    softmax_stats_kernel<<<1, 1024, 0, stream>>>(edge_w, stats);
    fwd_bucket_kernel<<<FWD_BUCKETS, 512, 0, stream>>>(h_user, pf, edge_w, buf, off, stats, rst);
    bwd_bucket_kernel<<<BWD_BUCKETS, 512, 0, stream>>>(rst, buf, off, out);
}

// Round 5
// 707.365 us; speedup vs baseline: 3.3044x; 2.7960x over previous
//
#include <hip/hip_runtime.h>
#include <hip/hip_bf16.h>
#include <math.h>

#define N_USERS 100000
#define N_ITEMS 50000
#define N_EDGES 2000000
#define D 64
#define N_NODES (N_ITEMS + N_USERS)   // 150000: [0,50000) items (fwd), [50000,150000) users (bwd)

// ---------------------------------------------------------------------------
// Degree count for both directions into one array (global int atomics).
// ---------------------------------------------------------------------------
__global__ void count_kernel(const int* __restrict__ src, const int* __restrict__ dst,
                             int* __restrict__ deg) {
    int stride = gridDim.x * blockDim.x;
    for (int e = blockIdx.x * blockDim.x + threadIdx.x; e < N_EDGES; e += stride) {
        atomicAdd(&deg[dst[e]], 1);
        atomicAdd(&deg[N_ITEMS + src[e]], 1);
    }
}

// ---------------------------------------------------------------------------
// Single-block exclusive scan; also initializes the running cursor array.
// out has n+1 entries.
// ---------------------------------------------------------------------------
__global__ void scan_excl(const int* __restrict__ in, int* __restrict__ out,
                          int* __restrict__ cur, int n) {
    const int T = 1024, E = 4;
    __shared__ int wsum[16];
    __shared__ int s_carry;
    if (threadIdx.x == 0) s_carry = 0;
    __syncthreads();

    int lane = threadIdx.x & 63;
    int wid  = threadIdx.x >> 6;

    for (int base = 0; base < n; base += T * E) {
        int idx0 = base + threadIdx.x * E;
        int v[E];
        int tot = 0;
#pragma unroll
        for (int e = 0; e < E; e++) {
            int i = idx0 + e;
            v[e] = (i < n) ? in[i] : 0;
            tot += v[e];
        }
        int incl = tot;
#pragma unroll
        for (int off = 1; off < 64; off <<= 1) {
            int t = __shfl_up(incl, off);
            if (lane >= off) incl += t;
        }
        if (lane == 63) wsum[wid] = incl;
        __syncthreads();
        if (wid == 0 && lane < 16) {
            int t = wsum[lane];
            int sc = t;
#pragma unroll
            for (int off = 1; off < 16; off <<= 1) {
                int u = __shfl_up(sc, off);
                if (lane >= off) sc += u;
            }
            wsum[lane] = sc - t;
        }
        __syncthreads();
        int wave_off = wsum[wid];
        int excl = s_carry + wave_off + incl - tot;
#pragma unroll
        for (int e = 0; e < E; e++) {
            int i = idx0 + e;
            if (i < n) { out[i] = excl; cur[i] = excl; }
            excl += v[e];
        }
        __syncthreads();
        if (threadIdx.x == T - 1) s_carry += wave_off + incl;
        __syncthreads();
    }
    if (threadIdx.x == 0) out[n] = s_carry;
}

// ---------------------------------------------------------------------------
// Node-major CSR fill, XCD-class partitioned: blockIdx%8 = class; a class owns
// a CONTIGUOUS node range (items: 6250/class, users: 12500/class), so each
// output region of buf is written by blocks on one XCD only -> full-line
// writebacks instead of cross-XCD partial-line amplification (R1: 245 MB).
// Edge data is re-read 8x (128 MB streaming) - cheap.
// ---------------------------------------------------------------------------
__global__ void fill_kernel(const int* __restrict__ src, const int* __restrict__ dst,
                            int* __restrict__ cur, int* __restrict__ buf) {
    int cls   = blockIdx.x & 7;
    int slice = blockIdx.x >> 3;               // 0..255
    const int per = (N_EDGES + 255) / 256;     // 7813
    int lo = slice * per;
    int hi = lo + per; if (hi > N_EDGES) hi = N_EDGES;
    for (int e = lo + threadIdx.x; e < hi; e += 256) {
        int s = src[e], d = dst[e];
        if (d / 6250 == cls) {                 // N_ITEMS/8
            int p = atomicAdd(&cur[d], 1);
            buf[p] = s;                        // fwd list: src ids, grouped by item
        }
        if (s / 12500 == cls) {                // N_USERS/8
            int p = atomicAdd(&cur[N_ITEMS + s], 1);
            buf[p] = d;                        // bwd list: dst ids, grouped by user
        }
    }
}

// ---------------------------------------------------------------------------
// Global softmax stats over edge_w[N_ITEMS]: stats[0]=max, stats[1]=sum(exp(x-max))
// ---------------------------------------------------------------------------
__global__ void softmax_stats_kernel(const float* __restrict__ w, float* __restrict__ stats) {
    __shared__ float red[16];
    int tid = threadIdx.x, lane = tid & 63, wid = tid >> 6;

    float m = -INFINITY;
    for (int i = tid; i < N_ITEMS; i += 1024) m = fmaxf(m, w[i]);
#pragma unroll
    for (int off = 32; off; off >>= 1) m = fmaxf(m, __shfl_xor(m, off));
    if (lane == 0) red[wid] = m;
    __syncthreads();
    if (tid == 0) {
        float t = red[0];
        for (int k = 1; k < 16; k++) t = fmaxf(t, red[k]);
        red[0] = t;
    }
    __syncthreads();
    m = red[0];
    __syncthreads();

    float s = 0.f;
    for (int i = tid; i < N_ITEMS; i += 1024) s += expf(w[i] - m);
#pragma unroll
    for (int off = 32; off; off >>= 1) s += __shfl_xor(s, off);
    if (lane == 0) red[wid] = s;
    __syncthreads();
    if (tid == 0) {
        float t = 0.f;
        for (int k = 0; k < 16; k++) t += red[k];
        stats[0] = m;
        stats[1] = t;
    }
}

// ---------------------------------------------------------------------------
// Forward: one wave per item, lane = feature, REGISTER accumulation (no
// atomics). Unroll-4 keeps 4 independent row gathers in flight. Fused epilogue.
// ---------------------------------------------------------------------------
__global__ __launch_bounds__(256) void fwd_kernel(
    const float* __restrict__ h_user, const float* __restrict__ pf,
    const float* __restrict__ edge_w, const int* __restrict__ off,
    const int* __restrict__ buf, const float* __restrict__ stats,
    float* __restrict__ rst) {
    int i = blockIdx.x * 4 + (threadIdx.x >> 6);
    int lane = threadIdx.x & 63;
    if (i >= N_ITEMS) return;
    int beg = off[i], end = off[i + 1];
    float acc = 0.f;
    int k = beg;
    for (; k + 4 <= end; k += 4) {
        int s0 = buf[k], s1 = buf[k + 1], s2 = buf[k + 2], s3 = buf[k + 3];
        float v0 = h_user[(size_t)s0 * D + lane];
        float v1 = h_user[(size_t)s1 * D + lane];
        float v2 = h_user[(size_t)s2 * D + lane];
        float v3 = h_user[(size_t)s3 * D + lane];
        acc += (v0 + v1) + (v2 + v3);
    }
    for (; k < end; k++) acc += h_user[(size_t)buf[k] * D + lane];

    float m = stats[0], ssum = stats[1];
    float deg = (float)(end - beg);
    if (deg < 1.f) deg = 1.f;
    float sc = expf(edge_w[i] - m) / (ssum * deg);
    rst[(size_t)i * D + lane] = (acc + 0.5f * tanhf(pf[(size_t)i * D + lane])) * sc;
}

// ---------------------------------------------------------------------------
// Backward: one wave per user; register accumulation over rst rows.
// ---------------------------------------------------------------------------
__global__ __launch_bounds__(256) void bwd_kernel(
    const float* __restrict__ rst, const int* __restrict__ off,
    const int* __restrict__ buf, float* __restrict__ out) {
    int u = blockIdx.x * 4 + (threadIdx.x >> 6);
    int lane = threadIdx.x & 63;
    if (u >= N_USERS) return;
    int beg = off[N_ITEMS + u], end = off[N_ITEMS + u + 1];
    float acc = 0.f;
    int k = beg;
    for (; k + 4 <= end; k += 4) {
        int d0 = buf[k], d1 = buf[k + 1], d2 = buf[k + 2], d3 = buf[k + 3];
        float v0 = rst[(size_t)d0 * D + lane];
        float v1 = rst[(size_t)d1 * D + lane];
        float v2 = rst[(size_t)d2 * D + lane];
        float v3 = rst[(size_t)d3 * D + lane];
        acc += (v0 + v1) + (v2 + v3);
    }
    for (; k < end; k++) acc += rst[(size_t)buf[k] * D + lane];

    float deg = (float)(end - beg);
    if (deg < 1.f) deg = 1.f;
    out[(size_t)u * D + lane] = acc / deg;
}

// ---------------------------------------------------------------------------
extern "C" void kernel_launch(void* const* d_in, const int* in_sizes, int n_in,
                              void* d_out, int out_size, void* d_ws, size_t ws_size,
                              hipStream_t stream) {
    const float* h_user = (const float*)d_in[0];   // [N_USERS, D]
    const float* pf     = (const float*)d_in[1];   // [N_ITEMS, D]
    const float* edge_w = (const float*)d_in[2];   // [N_ITEMS]
    const int*   src    = (const int*)d_in[3];     // [N_EDGES]
    const int*   dst    = (const int*)d_in[4];     // [N_EDGES]
    float* out = (float*)d_out;                    // [N_USERS, D]

    // workspace carve-up (~31.4 MB)
    char* p = (char*)d_ws;
    int* deg = (int*)p;       p += sizeof(int) * N_NODES;
    int* off = (int*)p;       p += sizeof(int) * (N_NODES + 1);
    int* cur = (int*)p;       p += sizeof(int) * N_NODES;
    int* buf = (int*)p;       p += sizeof(int) * (size_t)2 * N_EDGES;
    float* rst   = (float*)p; p += sizeof(float) * (size_t)N_ITEMS * D;
    float* stats = (float*)p; p += 2 * sizeof(float);

    hipMemsetAsync(deg, 0, sizeof(int) * N_NODES, stream);

    count_kernel<<<2048, 256, 0, stream>>>(src, dst, deg);
    scan_excl<<<1, 1024, 0, stream>>>(deg, off, cur, N_NODES);
    fill_kernel<<<2048, 256, 0, stream>>>(src, dst, cur, buf);
    softmax_stats_kernel<<<1, 1024, 0, stream>>>(edge_w, stats);
    fwd_kernel<<<(N_ITEMS + 3) / 4, 256, 0, stream>>>(h_user, pf, edge_w, off, buf, stats, rst);
    bwd_kernel<<<(N_USERS + 3) / 4, 256, 0, stream>>>(rst, off, buf, out);
}

// Round 6
// 386.730 us; speedup vs baseline: 6.0440x; 1.8291x over previous
//
#include <hip/hip_runtime.h>
#include <hip/hip_bf16.h>
#include <math.h>

#define N_USERS 100000
#define N_ITEMS 50000
#define N_EDGES 2000000
#define D 64

// Coarse bins: 512 nodes per bin.
#define FB_BINS 98                    // ceil(50000/512)  forward (by item)
#define BB_BINS 196                   // ceil(100000/512) backward (by user)
#define NBINS   (FB_BINS + BB_BINS)   // 294
#define CHUNK   2048                  // edges per binfill WG
#define NCHUNK  ((N_EDGES + CHUNK - 1) / CHUNK)   // 977
#define FWD_WGS 782                   // ceil(50000/64)
#define BWD_WGS 1563                  // ceil(100000/64)
#define CAP     4032                  // LDS sorted-list capacity (mean 2558, sd ~51)

// ---------------------------------------------------------------------------
// Histogram of coarse-bin sizes (294 bins, LDS-staged).
// ---------------------------------------------------------------------------
__global__ __launch_bounds__(256) void hist_kernel(
    const int* __restrict__ src, const int* __restrict__ dst, int* __restrict__ gh) {
    __shared__ int h[NBINS];
    for (int i = threadIdx.x; i < NBINS; i += 256) h[i] = 0;
    __syncthreads();
    int stride = gridDim.x * blockDim.x;
    for (int e = blockIdx.x * blockDim.x + threadIdx.x; e < N_EDGES; e += stride) {
        atomicAdd(&h[dst[e] >> 9], 1);
        atomicAdd(&h[FB_BINS + (src[e] >> 9)], 1);
    }
    __syncthreads();
    for (int i = threadIdx.x; i < NBINS; i += 256) {
        int v = h[i];
        if (v) atomicAdd(&gh[i], v);
    }
}

// ---------------------------------------------------------------------------
// Single-block exclusive scan; also initializes the running cursor array.
// ---------------------------------------------------------------------------
__global__ void scan_excl(const int* __restrict__ in, int* __restrict__ out,
                          int* __restrict__ cur, int n) {
    const int T = 1024, E = 4;
    __shared__ int wsum[16];
    __shared__ int s_carry;
    if (threadIdx.x == 0) s_carry = 0;
    __syncthreads();

    int lane = threadIdx.x & 63;
    int wid  = threadIdx.x >> 6;

    for (int base = 0; base < n; base += T * E) {
        int idx0 = base + threadIdx.x * E;
        int v[E];
        int tot = 0;
#pragma unroll
        for (int e = 0; e < E; e++) {
            int i = idx0 + e;
            v[e] = (i < n) ? in[i] : 0;
            tot += v[e];
        }
        int incl = tot;
#pragma unroll
        for (int off = 1; off < 64; off <<= 1) {
            int t = __shfl_up(incl, off);
            if (lane >= off) incl += t;
        }
        if (lane == 63) wsum[wid] = incl;
        __syncthreads();
        if (wid == 0 && lane < 16) {
            int t = wsum[lane];
            int sc = t;
#pragma unroll
            for (int off = 1; off < 16; off <<= 1) {
                int u = __shfl_up(sc, off);
                if (lane >= off) sc += u;
            }
            wsum[lane] = sc - t;
        }
        __syncthreads();
        int wave_off = wsum[wid];
        int excl = s_carry + wave_off + incl - tot;
#pragma unroll
        for (int e = 0; e < E; e++) {
            int i = idx0 + e;
            if (i < n) { out[i] = excl; cur[i] = excl; }
            excl += v[e];
        }
        __syncthreads();
        if (threadIdx.x == T - 1) s_carry += wave_off + incl;
        __syncthreads();
    }
    if (threadIdx.x == 0) out[n] = s_carry;
}

// ---------------------------------------------------------------------------
// binfill: chunk-aggregated scatter. Each WG keeps its 2048 edges in registers,
// LDS-histograms them over 294 bins, claims one global cursor range per
// (chunk,bin), then writes ~14-entry dense runs (~56 B) -> near-full-line
// writebacks instead of 4 B scatter (R5: 225 MB -> predict ~30 MB).
// fwd entry: s(17b) | d_local9<<17 ; bwd entry: d(16b) | s_local9<<16.
// ---------------------------------------------------------------------------
__global__ __launch_bounds__(256) void binfill_kernel(
    const int* __restrict__ src, const int* __restrict__ dst,
    int* __restrict__ gcur, unsigned* __restrict__ stage) {
    __shared__ int cnt[NBINS];
    __shared__ int gbase[NBINS];
    __shared__ int lcur[NBINS];
    int c = blockIdx.x;
    int base = c * CHUNK;
    int nEdge = N_EDGES - base; if (nEdge > CHUNK) nEdge = CHUNK;

    for (int t = threadIdx.x; t < NBINS; t += 256) { cnt[t] = 0; lcur[t] = 0; }
    __syncthreads();

    int es[8], ed[8];
#pragma unroll
    for (int j = 0; j < 8; j++) {
        int k = j * 256 + threadIdx.x;
        if (k < nEdge) {
            es[j] = src[base + k];
            ed[j] = dst[base + k];
            atomicAdd(&cnt[ed[j] >> 9], 1);
            atomicAdd(&cnt[FB_BINS + (es[j] >> 9)], 1);
        } else {
            es[j] = -1;
        }
    }
    __syncthreads();
    for (int t = threadIdx.x; t < NBINS; t += 256) {
        int cv = cnt[t];
        gbase[t] = cv ? atomicAdd(&gcur[t], cv) : 0;
    }
    __syncthreads();
#pragma unroll
    for (int j = 0; j < 8; j++) {
        if (es[j] >= 0) {
            int s = es[j], d = ed[j];
            int bf = d >> 9;
            int p = atomicAdd(&lcur[bf], 1);
            stage[gbase[bf] + p] = (unsigned)s | ((unsigned)(d & 511) << 17);
            int bb = FB_BINS + (s >> 9);
            int q = atomicAdd(&lcur[bb], 1);
            stage[gbase[bb] + q] = (unsigned)d | ((unsigned)(s & 511) << 16);
        }
    }
}

// ---------------------------------------------------------------------------
// Global softmax stats over edge_w[N_ITEMS]: stats[0]=max, stats[1]=sum(exp(x-max))
// ---------------------------------------------------------------------------
__global__ void softmax_stats_kernel(const float* __restrict__ w, float* __restrict__ stats) {
    __shared__ float red[16];
    int tid = threadIdx.x, lane = tid & 63, wid = tid >> 6;

    float m = -INFINITY;
    for (int i = tid; i < N_ITEMS; i += 1024) m = fmaxf(m, w[i]);
#pragma unroll
    for (int off = 32; off; off >>= 1) m = fmaxf(m, __shfl_xor(m, off));
    if (lane == 0) red[wid] = m;
    __syncthreads();
    if (tid == 0) {
        float t = red[0];
        for (int k = 1; k < 16; k++) t = fmaxf(t, red[k]);
        red[0] = t;
    }
    __syncthreads();
    m = red[0];
    __syncthreads();

    float s = 0.f;
    for (int i = tid; i < N_ITEMS; i += 1024) s += expf(w[i] - m);
#pragma unroll
    for (int off = 32; off; off >>= 1) s += __shfl_xor(s, off);
    if (lane == 0) red[wid] = s;
    __syncthreads();
    if (tid == 0) {
        float t = 0.f;
        for (int k = 0; k < 16; k++) t += red[k];
        stats[0] = m;
        stats[1] = t;
    }
}

// ---------------------------------------------------------------------------
// pass2 fwd: one 512-thread WG per 64 items. Filters parent bin's chunk
// (sub = r&7 of the 512-item bin), counting-sorts its ~2560 edges into LDS,
// then 8 waves do register-accumulated h_user gathers + fused epilogue.
// ---------------------------------------------------------------------------
__global__ __launch_bounds__(512) void pass2_fwd_kernel(
    const float* __restrict__ h_user, const float* __restrict__ pf,
    const float* __restrict__ edge_w, const unsigned* __restrict__ stage,
    const int* __restrict__ binoff, const float* __restrict__ stats,
    float* __restrict__ rst) {
    __shared__ int cnt[64];
    __shared__ int loc[65];
    __shared__ int lcur[64];
    __shared__ int sorted[CAP];
    int r = blockIdx.x;
    int B = r >> 3, sub = r & 7;
    int beg = binoff[B], end = binoff[B + 1];
    int tid = threadIdx.x, lane = tid & 63, wv = tid >> 6;

    if (tid < 64) { cnt[tid] = 0; lcur[tid] = 0; }
    __syncthreads();

    for (int k = beg + tid; k < end; k += 512) {
        unsigned e = stage[k];
        if ((int)(e >> 23) == sub) atomicAdd(&cnt[(e >> 17) & 63], 1);
    }
    __syncthreads();
    if (tid < 64) {   // wave 0: exclusive scan of 64 counts
        int v = cnt[tid];
        int incl = v;
#pragma unroll
        for (int off = 1; off < 64; off <<= 1) {
            int t = __shfl_up(incl, off);
            if (tid >= off) incl += t;
        }
        loc[tid] = incl - v;
        if (tid == 63) loc[64] = incl;
    }
    __syncthreads();
    int nf = loc[64];

    float m = stats[0], ssum = stats[1];

    if (nf <= CAP) {
        for (int k = beg + tid; k < end; k += 512) {
            unsigned e = stage[k];
            if ((int)(e >> 23) == sub) {
                int il = (e >> 17) & 63;
                int p = atomicAdd(&lcur[il], 1);
                sorted[loc[il] + p] = (int)(e & 0x1FFFFu);
            }
        }
        __syncthreads();
        for (int il = wv; il < 64; il += 8) {
            int i = r * 64 + il;
            if (i >= N_ITEMS) continue;
            int a = loc[il], b = loc[il + 1];
            float acc = 0.f;
            int k = a;
            for (; k + 4 <= b; k += 4) {
                int s0 = sorted[k], s1 = sorted[k + 1], s2 = sorted[k + 2], s3 = sorted[k + 3];
                float v0 = h_user[(size_t)s0 * D + lane];
                float v1 = h_user[(size_t)s1 * D + lane];
                float v2 = h_user[(size_t)s2 * D + lane];
                float v3 = h_user[(size_t)s3 * D + lane];
                acc += (v0 + v1) + (v2 + v3);
            }
            for (; k < b; k++) acc += h_user[(size_t)sorted[k] * D + lane];
            float deg = (float)(b - a);
            if (deg < 1.f) deg = 1.f;
            float sc = expf(edge_w[i] - m) / (ssum * deg);
            rst[(size_t)i * D + lane] = (acc + 0.5f * tanhf(pf[(size_t)i * D + lane])) * sc;
        }
    } else {
        // overflow fallback (statistically unreachable): per-item scan of chunk
        for (int il = wv; il < 64; il += 8) {
            int i = r * 64 + il;
            if (i >= N_ITEMS) continue;
            unsigned want = ((unsigned)sub << 6) | (unsigned)il;
            float acc = 0.f;
            int dcount = 0;
            for (int k = beg; k < end; k++) {
                unsigned e = stage[k];
                if ((e >> 17) == want) { acc += h_user[(size_t)(e & 0x1FFFFu) * D + lane]; dcount++; }
            }
            float deg = (float)dcount;
            if (deg < 1.f) deg = 1.f;
            float sc = expf(edge_w[i] - m) / (ssum * deg);
            rst[(size_t)i * D + lane] = (acc + 0.5f * tanhf(pf[(size_t)i * D + lane])) * sc;
        }
    }
}

// ---------------------------------------------------------------------------
// pass2 bwd: one 512-thread WG per 64 users; same plan over rst.
// ---------------------------------------------------------------------------
__global__ __launch_bounds__(512) void pass2_bwd_kernel(
    const float* __restrict__ rst, const unsigned* __restrict__ stage,
    const int* __restrict__ binoff, float* __restrict__ out) {
    __shared__ int cnt[64];
    __shared__ int loc[65];
    __shared__ int lcur[64];
    __shared__ int sorted[CAP];
    int r = blockIdx.x;
    int B = FB_BINS + (r >> 3), sub = r & 7;
    int beg = binoff[B], end = binoff[B + 1];
    int tid = threadIdx.x, lane = tid & 63, wv = tid >> 6;

    if (tid < 64) { cnt[tid] = 0; lcur[tid] = 0; }
    __syncthreads();

    for (int k = beg + tid; k < end; k += 512) {
        unsigned e = stage[k];
        if ((int)(e >> 22) == sub) atomicAdd(&cnt[(e >> 16) & 63], 1);
    }
    __syncthreads();
    if (tid < 64) {
        int v = cnt[tid];
        int incl = v;
#pragma unroll
        for (int off = 1; off < 64; off <<= 1) {
            int t = __shfl_up(incl, off);
            if (tid >= off) incl += t;
        }
        loc[tid] = incl - v;
        if (tid == 63) loc[64] = incl;
    }
    __syncthreads();
    int nf = loc[64];

    if (nf <= CAP) {
        for (int k = beg + tid; k < end; k += 512) {
            unsigned e = stage[k];
            if ((int)(e >> 22) == sub) {
                int il = (e >> 16) & 63;
                int p = atomicAdd(&lcur[il], 1);
                sorted[loc[il] + p] = (int)(e & 0xFFFFu);
            }
        }
        __syncthreads();
        for (int il = wv; il < 64; il += 8) {
            int u = r * 64 + il;
            if (u >= N_USERS) continue;
            int a = loc[il], b = loc[il + 1];
            float acc = 0.f;
            int k = a;
            for (; k + 4 <= b; k += 4) {
                int d0 = sorted[k], d1 = sorted[k + 1], d2 = sorted[k + 2], d3 = sorted[k + 3];
                float v0 = rst[(size_t)d0 * D + lane];
                float v1 = rst[(size_t)d1 * D + lane];
                float v2 = rst[(size_t)d2 * D + lane];
                float v3 = rst[(size_t)d3 * D + lane];
                acc += (v0 + v1) + (v2 + v3);
            }
            for (; k < b; k++) acc += rst[(size_t)sorted[k] * D + lane];
            float deg = (float)(b - a);
            if (deg < 1.f) deg = 1.f;
            out[(size_t)u * D + lane] = acc / deg;
        }
    } else {
        for (int il = wv; il < 64; il += 8) {
            int u = r * 64 + il;
            if (u >= N_USERS) continue;
            unsigned want = ((unsigned)sub << 6) | (unsigned)il;
            float acc = 0.f;
            int dcount = 0;
            for (int k = beg; k < end; k++) {
                unsigned e = stage[k];
                if ((e >> 16) == want) { acc += rst[(size_t)(e & 0xFFFFu) * D + lane]; dcount++; }
            }
            float deg = (float)dcount;
            if (deg < 1.f) deg = 1.f;
            out[(size_t)u * D + lane] = acc / deg;
        }
    }
}

// ---------------------------------------------------------------------------
extern "C" void kernel_launch(void* const* d_in, const int* in_sizes, int n_in,
                              void* d_out, int out_size, void* d_ws, size_t ws_size,
                              hipStream_t stream) {
    const float* h_user = (const float*)d_in[0];   // [N_USERS, D]
    const float* pf     = (const float*)d_in[1];   // [N_ITEMS, D]
    const float* edge_w = (const float*)d_in[2];   // [N_ITEMS]
    const int*   src    = (const int*)d_in[3];     // [N_EDGES]
    const int*   dst    = (const int*)d_in[4];     // [N_EDGES]
    float* out = (float*)d_out;                    // [N_USERS, D]

    // workspace carve-up (~28.8 MB)
    char* p = (char*)d_ws;
    int* gh     = (int*)p;      p += sizeof(int) * NBINS;
    int* binoff = (int*)p;      p += sizeof(int) * (NBINS + 1);
    int* gcur   = (int*)p;      p += sizeof(int) * NBINS;
    unsigned* stage = (unsigned*)p; p += sizeof(unsigned) * (size_t)2 * N_EDGES;
    float* rst   = (float*)p;   p += sizeof(float) * (size_t)N_ITEMS * D;
    float* stats = (float*)p;   p += 2 * sizeof(float);

    hipMemsetAsync(gh, 0, sizeof(int) * NBINS, stream);

    hist_kernel<<<256, 256, 0, stream>>>(src, dst, gh);
    scan_excl<<<1, 1024, 0, stream>>>(gh, binoff, gcur, NBINS);
    binfill_kernel<<<NCHUNK, 256, 0, stream>>>(src, dst, gcur, stage);
    softmax_stats_kernel<<<1, 1024, 0, stream>>>(edge_w, stats);
    pass2_fwd_kernel<<<FWD_WGS, 512, 0, stream>>>(h_user, pf, edge_w, stage, binoff, stats, rst);
    pass2_bwd_kernel<<<BWD_WGS, 512, 0, stream>>>(rst, stage, binoff, out);
}

// Round 7
// 348.318 us; speedup vs baseline: 6.7106x; 1.1103x over previous
//
#include <hip/hip_runtime.h>
#include <hip/hip_bf16.h>
#include <math.h>

#define N_USERS 100000
#define N_ITEMS 50000
#define N_EDGES 2000000
#define D 64

// Coarse bins: 512 nodes per bin.
#define FB_BINS 98                    // ceil(50000/512)  forward (by item)
#define BB_BINS 196                   // ceil(100000/512) backward (by user)
#define NBINS   (FB_BINS + BB_BINS)   // 294
#define CHUNK   2048                  // edges per binfill WG
#define NCHUNK  ((N_EDGES + CHUNK - 1) / CHUNK)   // 977
#define FWD_WGS 782                   // ceil(50000/64)
#define BWD_WGS 1563                  // ceil(100000/64)
#define CAP     4032                  // LDS sorted-list capacity (mean 2558, sd ~51)

// ---- bf16 pack/unpack helpers --------------------------------------------
__device__ __forceinline__ float blo(unsigned u) {
    union { unsigned i; float f; } c; c.i = u << 16; return c.f;
}
__device__ __forceinline__ float bhi(unsigned u) {
    union { unsigned i; float f; } c; c.i = u & 0xFFFF0000u; return c.f;
}
__device__ __forceinline__ unsigned bpack(float x, float y) {
    __hip_bfloat16 a = __float2bfloat16(x), b = __float2bfloat16(y);
    unsigned short ua = *reinterpret_cast<unsigned short*>(&a);
    unsigned short ub = *reinterpret_cast<unsigned short*>(&b);
    return (unsigned)ua | ((unsigned)ub << 16);
}

// ---------------------------------------------------------------------------
// Convert h_user fp32 -> packed bf16 pairs (hu16): one uint = features 2q,2q+1.
// ---------------------------------------------------------------------------
__global__ __launch_bounds__(256) void h2b_kernel(
    const float2* __restrict__ in, unsigned* __restrict__ out, int n) {
    int stride = gridDim.x * blockDim.x;
    for (int i = blockIdx.x * blockDim.x + threadIdx.x; i < n; i += stride) {
        float2 v = in[i];
        out[i] = bpack(v.x, v.y);
    }
}

// ---------------------------------------------------------------------------
// Histogram of coarse-bin sizes (294 bins, LDS-staged).
// ---------------------------------------------------------------------------
__global__ __launch_bounds__(256) void hist_kernel(
    const int* __restrict__ src, const int* __restrict__ dst, int* __restrict__ gh) {
    __shared__ int h[NBINS];
    for (int i = threadIdx.x; i < NBINS; i += 256) h[i] = 0;
    __syncthreads();
    int stride = gridDim.x * blockDim.x;
    for (int e = blockIdx.x * blockDim.x + threadIdx.x; e < N_EDGES; e += stride) {
        atomicAdd(&h[dst[e] >> 9], 1);
        atomicAdd(&h[FB_BINS + (src[e] >> 9)], 1);
    }
    __syncthreads();
    for (int i = threadIdx.x; i < NBINS; i += 256) {
        int v = h[i];
        if (v) atomicAdd(&gh[i], v);
    }
}

// ---------------------------------------------------------------------------
// Single-block exclusive scan; also initializes the running cursor array.
// ---------------------------------------------------------------------------
__global__ void scan_excl(const int* __restrict__ in, int* __restrict__ out,
                          int* __restrict__ cur, int n) {
    const int T = 1024, E = 4;
    __shared__ int wsum[16];
    __shared__ int s_carry;
    if (threadIdx.x == 0) s_carry = 0;
    __syncthreads();

    int lane = threadIdx.x & 63;
    int wid  = threadIdx.x >> 6;

    for (int base = 0; base < n; base += T * E) {
        int idx0 = base + threadIdx.x * E;
        int v[E];
        int tot = 0;
#pragma unroll
        for (int e = 0; e < E; e++) {
            int i = idx0 + e;
            v[e] = (i < n) ? in[i] : 0;
            tot += v[e];
        }
        int incl = tot;
#pragma unroll
        for (int off = 1; off < 64; off <<= 1) {
            int t = __shfl_up(incl, off);
            if (lane >= off) incl += t;
        }
        if (lane == 63) wsum[wid] = incl;
        __syncthreads();
        if (wid == 0 && lane < 16) {
            int t = wsum[lane];
            int sc = t;
#pragma unroll
            for (int off = 1; off < 16; off <<= 1) {
                int u = __shfl_up(sc, off);
                if (lane >= off) sc += u;
            }
            wsum[lane] = sc - t;
        }
        __syncthreads();
        int wave_off = wsum[wid];
        int excl = s_carry + wave_off + incl - tot;
#pragma unroll
        for (int e = 0; e < E; e++) {
            int i = idx0 + e;
            if (i < n) { out[i] = excl; cur[i] = excl; }
            excl += v[e];
        }
        __syncthreads();
        if (threadIdx.x == T - 1) s_carry += wave_off + incl;
        __syncthreads();
    }
    if (threadIdx.x == 0) out[n] = s_carry;
}

// ---------------------------------------------------------------------------
// binfill: chunk-aggregated scatter (dense ~56 B runs per (chunk,bin)).
// fwd entry: s(17b) | d_local9<<17 ; bwd entry: d(16b) | s_local9<<16.
// ---------------------------------------------------------------------------
__global__ __launch_bounds__(256) void binfill_kernel(
    const int* __restrict__ src, const int* __restrict__ dst,
    int* __restrict__ gcur, unsigned* __restrict__ stage) {
    __shared__ int cnt[NBINS];
    __shared__ int gbase[NBINS];
    __shared__ int lcur[NBINS];
    int c = blockIdx.x;
    int base = c * CHUNK;
    int nEdge = N_EDGES - base; if (nEdge > CHUNK) nEdge = CHUNK;

    for (int t = threadIdx.x; t < NBINS; t += 256) { cnt[t] = 0; lcur[t] = 0; }
    __syncthreads();

    int es[8], ed[8];
#pragma unroll
    for (int j = 0; j < 8; j++) {
        int k = j * 256 + threadIdx.x;
        if (k < nEdge) {
            es[j] = src[base + k];
            ed[j] = dst[base + k];
            atomicAdd(&cnt[ed[j] >> 9], 1);
            atomicAdd(&cnt[FB_BINS + (es[j] >> 9)], 1);
        } else {
            es[j] = -1;
        }
    }
    __syncthreads();
    for (int t = threadIdx.x; t < NBINS; t += 256) {
        int cv = cnt[t];
        gbase[t] = cv ? atomicAdd(&gcur[t], cv) : 0;
    }
    __syncthreads();
#pragma unroll
    for (int j = 0; j < 8; j++) {
        if (es[j] >= 0) {
            int s = es[j], d = ed[j];
            int bf = d >> 9;
            int p = atomicAdd(&lcur[bf], 1);
            stage[gbase[bf] + p] = (unsigned)s | ((unsigned)(d & 511) << 17);
            int bb = FB_BINS + (s >> 9);
            int q = atomicAdd(&lcur[bb], 1);
            stage[gbase[bb] + q] = (unsigned)d | ((unsigned)(s & 511) << 16);
        }
    }
}

// ---------------------------------------------------------------------------
// Global softmax stats over edge_w[N_ITEMS]: stats[0]=max, stats[1]=sum(exp(x-max))
// ---------------------------------------------------------------------------
__global__ void softmax_stats_kernel(const float* __restrict__ w, float* __restrict__ stats) {
    __shared__ float red[16];
    int tid = threadIdx.x, lane = tid & 63, wid = tid >> 6;

    float m = -INFINITY;
    for (int i = tid; i < N_ITEMS; i += 1024) m = fmaxf(m, w[i]);
#pragma unroll
    for (int off = 32; off; off >>= 1) m = fmaxf(m, __shfl_xor(m, off));
    if (lane == 0) red[wid] = m;
    __syncthreads();
    if (tid == 0) {
        float t = red[0];
        for (int k = 1; k < 16; k++) t = fmaxf(t, red[k]);
        red[0] = t;
    }
    __syncthreads();
    m = red[0];
    __syncthreads();

    float s = 0.f;
    for (int i = tid; i < N_ITEMS; i += 1024) s += expf(w[i] - m);
#pragma unroll
    for (int off = 32; off; off >>= 1) s += __shfl_xor(s, off);
    if (lane == 0) red[wid] = s;
    __syncthreads();
    if (tid == 0) {
        float t = 0.f;
        for (int k = 0; k < 16; k++) t += red[k];
        stats[0] = m;
        stats[1] = t;
    }
}

// ---------------------------------------------------------------------------
// pass2 fwd: one 512-thread WG per 64 items. Counting-sort parent-bin edges
// into LDS, then 8 waves gather bf16 h_user rows: 2 edges/wave-load (half-wave
// per edge, uint = 2 bf16 features per lane), register accumulation, fused
// epilogue, bf16 rst output.
// ---------------------------------------------------------------------------
__global__ __launch_bounds__(512) void pass2_fwd_kernel(
    const unsigned* __restrict__ hu16, const float* __restrict__ pf,
    const float* __restrict__ edge_w, const unsigned* __restrict__ stage,
    const int* __restrict__ binoff, const float* __restrict__ stats,
    unsigned* __restrict__ rst16) {
    __shared__ int cnt[64];
    __shared__ int loc[65];
    __shared__ int lcur[64];
    __shared__ int sorted[CAP];
    int r = blockIdx.x;
    int B = r >> 3, sub = r & 7;
    int beg = binoff[B], end = binoff[B + 1];
    int tid = threadIdx.x, lane = tid & 63, wv = tid >> 6;
    int q = lane & 31, half = lane >> 5;

    if (tid < 64) { cnt[tid] = 0; lcur[tid] = 0; }
    __syncthreads();

    for (int k = beg + tid; k < end; k += 512) {
        unsigned e = stage[k];
        if ((int)(e >> 23) == sub) atomicAdd(&cnt[(e >> 17) & 63], 1);
    }
    __syncthreads();
    if (tid < 64) {   // wave 0: exclusive scan of 64 counts
        int v = cnt[tid];
        int incl = v;
#pragma unroll
        for (int off = 1; off < 64; off <<= 1) {
            int t = __shfl_up(incl, off);
            if (tid >= off) incl += t;
        }
        loc[tid] = incl - v;
        if (tid == 63) loc[64] = incl;
    }
    __syncthreads();
    int nf = loc[64];

    float m = stats[0], ssum = stats[1];
    const float2* PF2 = (const float2*)pf;

    if (nf <= CAP) {
        for (int k = beg + tid; k < end; k += 512) {
            unsigned e = stage[k];
            if ((int)(e >> 23) == sub) {
                int il = (e >> 17) & 63;
                int p = atomicAdd(&lcur[il], 1);
                sorted[loc[il] + p] = (int)(e & 0x1FFFFu);
            }
        }
        __syncthreads();
        for (int il = wv; il < 64; il += 8) {
            int i = r * 64 + il;
            if (i >= N_ITEMS) continue;
            int a = loc[il], b = loc[il + 1];
            float ax = 0.f, ay = 0.f;
            int k = a;
            for (; k + 8 <= b; k += 8) {
                int s0 = sorted[k + half],     s1 = sorted[k + 2 + half];
                int s2 = sorted[k + 4 + half], s3 = sorted[k + 6 + half];
                unsigned u0 = hu16[(s0 << 5) + q];
                unsigned u1 = hu16[(s1 << 5) + q];
                unsigned u2 = hu16[(s2 << 5) + q];
                unsigned u3 = hu16[(s3 << 5) + q];
                ax += (blo(u0) + blo(u1)) + (blo(u2) + blo(u3));
                ay += (bhi(u0) + bhi(u1)) + (bhi(u2) + bhi(u3));
            }
            for (; k + 2 <= b; k += 2) {
                unsigned u = hu16[(sorted[k + half] << 5) + q];
                ax += blo(u); ay += bhi(u);
            }
            if (k < b && half == 0) {
                unsigned u = hu16[(sorted[k] << 5) + q];
                ax += blo(u); ay += bhi(u);
            }
            ax += __shfl_xor(ax, 32);
            ay += __shfl_xor(ay, 32);
            if (half == 0) {
                float deg = (float)(b - a);
                if (deg < 1.f) deg = 1.f;
                float sc = expf(edge_w[i] - m) / (ssum * deg);
                float2 pv = PF2[(size_t)i * 32 + q];
                float vx = (ax + 0.5f * tanhf(pv.x)) * sc;
                float vy = (ay + 0.5f * tanhf(pv.y)) * sc;
                rst16[(size_t)i * 32 + q] = bpack(vx, vy);
            }
        }
    } else {
        // overflow fallback (statistically unreachable): per-item scan of bin
        const unsigned short* HU = (const unsigned short*)hu16;
        for (int il = wv; il < 64; il += 8) {
            int i = r * 64 + il;
            if (i >= N_ITEMS) continue;
            unsigned want = ((unsigned)sub << 6) | (unsigned)il;
            float acc = 0.f;
            int dcount = 0;
            for (int k = beg; k < end; k++) {
                unsigned e = stage[k];
                if ((e >> 17) == want) {
                    union { unsigned u; float f; } c;
                    c.u = (unsigned)HU[(size_t)(e & 0x1FFFFu) * 64 + lane] << 16;
                    acc += c.f; dcount++;
                }
            }
            float deg = (float)dcount;
            if (deg < 1.f) deg = 1.f;
            float sc = expf(edge_w[i] - m) / (ssum * deg);
            float val = (acc + 0.5f * tanhf(pf[(size_t)i * D + lane])) * sc;
            float va = __shfl(val, 2 * q);
            float vb = __shfl(val, 2 * q + 1);
            if (half == 0) rst16[(size_t)i * 32 + q] = bpack(va, vb);
        }
    }
}

// ---------------------------------------------------------------------------
// pass2 bwd: one 512-thread WG per 64 users; same plan over bf16 rst.
// ---------------------------------------------------------------------------
__global__ __launch_bounds__(512) void pass2_bwd_kernel(
    const unsigned* __restrict__ rst16, const unsigned* __restrict__ stage,
    const int* __restrict__ binoff, float* __restrict__ out) {
    __shared__ int cnt[64];
    __shared__ int loc[65];
    __shared__ int lcur[64];
    __shared__ int sorted[CAP];
    int r = blockIdx.x;
    int B = FB_BINS + (r >> 3), sub = r & 7;
    int beg = binoff[B], end = binoff[B + 1];
    int tid = threadIdx.x, lane = tid & 63, wv = tid >> 6;
    int q = lane & 31, half = lane >> 5;

    if (tid < 64) { cnt[tid] = 0; lcur[tid] = 0; }
    __syncthreads();

    for (int k = beg + tid; k < end; k += 512) {
        unsigned e = stage[k];
        if ((int)(e >> 22) == sub) atomicAdd(&cnt[(e >> 16) & 63], 1);
    }
    __syncthreads();
    if (tid < 64) {
        int v = cnt[tid];
        int incl = v;
#pragma unroll
        for (int off = 1; off < 64; off <<= 1) {
            int t = __shfl_up(incl, off);
            if (tid >= off) incl += t;
        }
        loc[tid] = incl - v;
        if (tid == 63) loc[64] = incl;
    }
    __syncthreads();
    int nf = loc[64];

    float2* OUT2 = (float2*)out;

    if (nf <= CAP) {
        for (int k = beg + tid; k < end; k += 512) {
            unsigned e = stage[k];
            if ((int)(e >> 22) == sub) {
                int il = (e >> 16) & 63;
                int p = atomicAdd(&lcur[il], 1);
                sorted[loc[il] + p] = (int)(e & 0xFFFFu);
            }
        }
        __syncthreads();
        for (int il = wv; il < 64; il += 8) {
            int u = r * 64 + il;
            if (u >= N_USERS) continue;
            int a = loc[il], b = loc[il + 1];
            float ax = 0.f, ay = 0.f;
            int k = a;
            for (; k + 8 <= b; k += 8) {
                int d0 = sorted[k + half],     d1 = sorted[k + 2 + half];
                int d2 = sorted[k + 4 + half], d3 = sorted[k + 6 + half];
                unsigned u0 = rst16[(d0 << 5) + q];
                unsigned u1 = rst16[(d1 << 5) + q];
                unsigned u2 = rst16[(d2 << 5) + q];
                unsigned u3 = rst16[(d3 << 5) + q];
                ax += (blo(u0) + blo(u1)) + (blo(u2) + blo(u3));
                ay += (bhi(u0) + bhi(u1)) + (bhi(u2) + bhi(u3));
            }
            for (; k + 2 <= b; k += 2) {
                unsigned e = rst16[(sorted[k + half] << 5) + q];
                ax += blo(e); ay += bhi(e);
            }
            if (k < b && half == 0) {
                unsigned e = rst16[(sorted[k] << 5) + q];
                ax += blo(e); ay += bhi(e);
            }
            ax += __shfl_xor(ax, 32);
            ay += __shfl_xor(ay, 32);
            if (half == 0) {
                float deg = (float)(b - a);
                if (deg < 1.f) deg = 1.f;
                OUT2[(size_t)u * 32 + q] = make_float2(ax / deg, ay / deg);
            }
        }
    } else {
        const unsigned short* RS = (const unsigned short*)rst16;
        for (int il = wv; il < 64; il += 8) {
            int u = r * 64 + il;
            if (u >= N_USERS) continue;
            unsigned want = ((unsigned)sub << 6) | (unsigned)il;
            float acc = 0.f;
            int dcount = 0;
            for (int k = beg; k < end; k++) {
                unsigned e = stage[k];
                if ((e >> 16) == want) {
                    union { unsigned ui; float f; } c;
                    c.ui = (unsigned)RS[(size_t)(e & 0xFFFFu) * 64 + lane] << 16;
                    acc += c.f; dcount++;
                }
            }
            float deg = (float)dcount;
            if (deg < 1.f) deg = 1.f;
            out[(size_t)u * D + lane] = acc / deg;
        }
    }
}

// ---------------------------------------------------------------------------
extern "C" void kernel_launch(void* const* d_in, const int* in_sizes, int n_in,
                              void* d_out, int out_size, void* d_ws, size_t ws_size,
                              hipStream_t stream) {
    const float* h_user = (const float*)d_in[0];   // [N_USERS, D]
    const float* pf     = (const float*)d_in[1];   // [N_ITEMS, D]
    const float* edge_w = (const float*)d_in[2];   // [N_ITEMS]
    const int*   src    = (const int*)d_in[3];     // [N_EDGES]
    const int*   dst    = (const int*)d_in[4];     // [N_EDGES]
    float* out = (float*)d_out;                    // [N_USERS, D]

    // workspace carve-up (~35.3 MB)
    char* p = (char*)d_ws;
    int* gh     = (int*)p;      p += sizeof(int) * NBINS;
    int* binoff = (int*)p;      p += sizeof(int) * (NBINS + 1);
    int* gcur   = (int*)p;      p += sizeof(int) * NBINS;
    unsigned* stage = (unsigned*)p; p += sizeof(unsigned) * (size_t)2 * N_EDGES;
    unsigned* hu16  = (unsigned*)p; p += sizeof(unsigned) * (size_t)N_USERS * 32;
    unsigned* rst16 = (unsigned*)p; p += sizeof(unsigned) * (size_t)N_ITEMS * 32;
    float* stats = (float*)p;   p += 2 * sizeof(float);

    hipMemsetAsync(gh, 0, sizeof(int) * NBINS, stream);

    hist_kernel<<<256, 256, 0, stream>>>(src, dst, gh);
    scan_excl<<<1, 1024, 0, stream>>>(gh, binoff, gcur, NBINS);
    binfill_kernel<<<NCHUNK, 256, 0, stream>>>(src, dst, gcur, stage);
    h2b_kernel<<<1024, 256, 0, stream>>>((const float2*)h_user, hu16, N_USERS * 32);
    softmax_stats_kernel<<<1, 1024, 0, stream>>>(edge_w, stats);
    pass2_fwd_kernel<<<FWD_WGS, 512, 0, stream>>>(hu16, pf, edge_w, stage, binoff, stats, rst16);
    pass2_bwd_kernel<<<BWD_WGS, 512, 0, stream>>>(rst16, stage, binoff, out);
}